// Round 14
// baseline (306.863 us; speedup 1.0000x reference)
//
#include <hip/hip_runtime.h>
#include <hip/hip_bf16.h>

#define H 1024
#define T 2048
#define B 32
#define BM 64         // rows per block (t-tile)
#define BKC 128       // k per LDS chunk
#define NCHUNK 8      // H / BKC

typedef __attribute__((ext_vector_type(8))) __bf16 bf16x8;
typedef __attribute__((ext_vector_type(16))) float f32x16;
typedef __attribute__((ext_vector_type(8))) unsigned short u16x8;

__device__ __forceinline__ unsigned short f2bf(float f) {
    unsigned int x = __float_as_uint(f);
    x += 0x7fffu + ((x >> 16) & 1u);
    return (unsigned short)(x >> 16);
}

__device__ __forceinline__ float fast_tanh(float x) {
    float t = __expf(2.0f * x);
    return 1.0f - 2.0f * __builtin_amdgcn_rcpf(t + 1.0f);
}

// Pack W2 = W[:, H:2H] into bf16, layout Wp[kg][n][8] (kg = k>>3), 16B per (kg,n)
__global__ __launch_bounds__(256) void prep_w_kernel(const float* __restrict__ W,
                                                     unsigned short* __restrict__ Wp) {
    int gid = blockIdx.x * 256 + threadIdx.x;   // 131072 total
    int n = gid & (H - 1);
    int kg = gid >> 10;                          // 0..127
    const float* srcp = W + (size_t)n * (2 * H) + H + kg * 8;
    float4 f0 = *(const float4*)(srcp);
    float4 f1 = *(const float4*)(srcp + 4);
    u16x8 o;
    o[0] = f2bf(f0.x); o[1] = f2bf(f0.y); o[2] = f2bf(f0.z); o[3] = f2bf(f0.w);
    o[4] = f2bf(f1.x); o[5] = f2bf(f1.y); o[6] = f2bf(f1.z); o[7] = f2bf(f1.w);
    *(u16x8*)(Wp + (size_t)gid * 8) = o;
}

// hp[b][h] = sum_d hidden[b][d]*W[h][d] + bias[h], k-split x4 + shuffle reduce
__global__ __launch_bounds__(256) void prep_hp_kernel(const float* __restrict__ hidden,
                                                      const float* __restrict__ W,
                                                      const float* __restrict__ bias,
                                                      float* __restrict__ hp) {
    int b = blockIdx.y;
    int t = threadIdx.x;
    int h = blockIdx.x * 64 + (t >> 2);
    int kq = t & 3;
    const float* hid = hidden + (size_t)b * H + kq * 256;
    const float* wr = W + (size_t)h * (2 * H) + kq * 256;
    float acc = 0.f;
#pragma unroll 4
    for (int d = 0; d < 256; d += 4) {
        float4 wv = *(const float4*)(wr + d);
        float4 hv = *(const float4*)(hid + d);
        acc += wv.x * hv.x + wv.y * hv.y + wv.z * hv.z + wv.w * hv.w;
    }
    acc += __shfl_xor(acc, 1);
    acc += __shfl_xor(acc, 2);
    if (kq == 0) hp[(size_t)b * H + h] = acc + bias[h];
}

#define MFMA32(A, Bv, C) __builtin_amdgcn_mfma_f32_32x32x16_bf16(A, Bv, C, 0, 0, 0)

// R10 structure + PER-WAVE PHASE ROTATION (convoy breaker):
// block = (64-row t-tile, b), 1024 thr = 16 waves; wave w owns cols [64w,64w+64).
// Within chunk j, wave w processes k-steps in rotated order p = (i + w) & 7, so the
// 16 waves are spread across all 8 phases at any instant -> one wave's MFMA overlaps
// another wave's B-return / LDS read instead of the block ping-ponging in lockstep.
// (Accumulation is k-order-independent; fp reordering is far below tolerance.)
// A: enc fp32 read once, reg-staged -> bf16 LDS, double-buffered; stage-issue at chunk
// top, ds_write at chunk end; plain __syncthreads chunk barrier (best measured, R10).
// B: Wp bf16 from L2, branchless wrapped depth-2 rolling prefetch, per-wave sequence
// indexed by logical step i (slot parity i&1), rotated nit = (j + ((i+2)>>3))*8 +
// ((i+2+w)&7), &63 tail-wrap (wrapped loads never consumed).
// LDS layout (proven 0-conflict): page ks (0..15) -> ks*1024 + ((row^(ks&7))<<4).
__global__ __launch_bounds__(1024, 4) void energy_kernel(const float* __restrict__ enc,
                                                         const float* __restrict__ hp,
                                                         const float* __restrict__ vvec,
                                                         const unsigned short* __restrict__ Wp,
                                                         float* __restrict__ scores) {
    __shared__ __align__(16) unsigned short Abuf[2][BM * BKC];  // 2 x 16 KB
    __shared__ float scpart[16][BM];                            // 4 KB

    const int tid = threadIdx.x;
    const int b = blockIdx.y;
    const int t0 = blockIdx.x * BM;
    const int wave = tid >> 6;
    const int lane = tid & 63;
    const int l31 = lane & 31;
    const int hi = lane >> 5;
    const int wph = wave & 7;        // per-wave phase rotation

    // staging: thread -> (row = tid>>4 in 0..63, kf = tid&15); 32B fp32 -> 16B bf16
    const int st_row = tid >> 4;
    const int st_kf = tid & 15;
    const float* st_src = enc + ((size_t)b * T + t0 + st_row) * H + st_kf * 8;
    char* Ab0 = (char*)&Abuf[0][0];
    char* st_dst = Ab0 + st_kf * 1024 + (((st_row ^ (st_kf & 7))) << 4);

    // B stream: k-step nit (0..63): page kg = nit*2 + hi; col = wave*64 + {l31, l31+32}
    const unsigned short* wp_base = Wp + (size_t)(wave * 64 + l31) * 8 + (size_t)hi * (H * 8);

    f32x16 acc00, acc01, acc10, acc11;
#pragma unroll
    for (int i = 0; i < 16; ++i) { acc00[i] = 0.f; acc01[i] = 0.f; acc10[i] = 0.f; acc11[i] = 0.f; }

    const int rv0 = l31;        // a0 rows 0..31
    const int rv1 = 32 + l31;   // a1 rows 32..63

    // ---- prologue: stage chunk 0; preload B for this wave's first two steps ----
    {
        float4 f0 = *(const float4*)(st_src);
        float4 f1 = *(const float4*)(st_src + 4);
        u16x8 o;
        o[0] = f2bf(f0.x); o[1] = f2bf(f0.y); o[2] = f2bf(f0.z); o[3] = f2bf(f0.w);
        o[4] = f2bf(f1.x); o[5] = f2bf(f1.y); o[6] = f2bf(f1.z); o[7] = f2bf(f1.w);
        *(u16x8*)st_dst = o;
    }
    // step i=0 -> phase wph -> nit = wph; step i=1 -> nit = (wph+1)&7
    bf16x8 bA0 = *(const bf16x8*)(wp_base + (size_t)wph * (H * 16));
    bf16x8 bA1 = *(const bf16x8*)(wp_base + (size_t)wph * (H * 16) + 256);
    bf16x8 bB0 = *(const bf16x8*)(wp_base + (size_t)((wph + 1) & 7) * (H * 16));
    bf16x8 bB1 = *(const bf16x8*)(wp_base + (size_t)((wph + 1) & 7) * (H * 16) + 256);
    __syncthreads();

    // At logical step KI of chunk j, slots hold B for k-step j*8 + ((KI+wph)&7);
    // reload the step-(KI+2) B: nit = (j + ((KI+2)>>3))*8 + ((KI+2+wph)&7), &63 wrap.
#define PH(KI, C0, C1)                                                         \
    {                                                                          \
        const int ks = (((KI) + wph) & 7) * 2 + hi;                            \
        const char* ap = Ab + ks * 1024;                                       \
        bf16x8 a0 = *(const bf16x8*)(ap + ((rv0 ^ (ks & 7)) << 4));            \
        bf16x8 a1 = *(const bf16x8*)(ap + ((rv1 ^ (ks & 7)) << 4));            \
        __builtin_amdgcn_s_setprio(1);                                         \
        acc00 = MFMA32(a0, C0, acc00);                                         \
        acc01 = MFMA32(a0, C1, acc01);                                         \
        acc10 = MFMA32(a1, C0, acc10);                                         \
        acc11 = MFMA32(a1, C1, acc11);                                         \
        __builtin_amdgcn_s_setprio(0);                                         \
        const int nitw = ((j + (((KI) + 2) >> 3)) * 8 + (((KI) + 2 + wph) & 7)) & 63; \
        const unsigned short* bp = wp_base + (size_t)nitw * (H * 16);          \
        C0 = *(const bf16x8*)(bp);                                             \
        C1 = *(const bf16x8*)(bp + 256);                                       \
    }

    for (int j = 0; j < NCHUNK; ++j) {
        // issue next chunk's A loads early (T14: load-early, write-late)
        float4 f0, f1;
        const bool pfA = (j < NCHUNK - 1);
        if (pfA) {
            const float* p = st_src + (j + 1) * BKC;
            f0 = *(const float4*)(p);
            f1 = *(const float4*)(p + 4);
        }
        const char* Ab = Ab0 + (j & 1) * 16384;
        PH(0, bA0, bA1)
        PH(1, bB0, bB1)
        PH(2, bA0, bA1)
        PH(3, bB0, bB1)
        PH(4, bA0, bA1)
        PH(5, bB0, bB1)
        PH(6, bA0, bA1)
        PH(7, bB0, bB1)
        if (pfA) {
            u16x8 o;
            o[0] = f2bf(f0.x); o[1] = f2bf(f0.y); o[2] = f2bf(f0.z); o[3] = f2bf(f0.w);
            o[4] = f2bf(f1.x); o[5] = f2bf(f1.y); o[6] = f2bf(f1.z); o[7] = f2bf(f1.w);
            *(u16x8*)(st_dst + ((j + 1) & 1) * 16384) = o;
        }
        __syncthreads();
    }
#undef PH

    // ---- fused epilogue: tanh + v-dot over this wave's 64 cols ----
    const size_t bH = (size_t)b * H;
    const int col0 = wave * 64 + l31;
    const int col1 = col0 + 32;
    const float hp0 = hp[bH + col0], hp1 = hp[bH + col1];
    const float v0 = vvec[col0], v1 = vvec[col1];
    float psc[2][16];
#pragma unroll
    for (int r = 0; r < 16; ++r) {
        psc[0][r] = v0 * fast_tanh(acc00[r] + hp0) + v1 * fast_tanh(acc01[r] + hp1);
        psc[1][r] = v0 * fast_tanh(acc10[r] + hp0) + v1 * fast_tanh(acc11[r] + hp1);
    }

#pragma unroll
    for (int rg = 0; rg < 2; ++rg)
#pragma unroll
        for (int r = 0; r < 16; ++r) {
            float s = psc[rg][r];
            s += __shfl_xor(s, 1);
            s += __shfl_xor(s, 2);
            s += __shfl_xor(s, 4);
            s += __shfl_xor(s, 8);
            s += __shfl_xor(s, 16);
            psc[rg][r] = s;
        }
    if (l31 == 0) {
#pragma unroll
        for (int rg = 0; rg < 2; ++rg)
#pragma unroll
            for (int r = 0; r < 16; ++r) {
                int m = rg * 32 + (r & 3) + 8 * (r >> 2) + 4 * hi;
                scpart[wave][m] = psc[rg][r];
            }
    }
    __syncthreads();
    if (tid < BM) {
        float s = 0.f;
#pragma unroll
        for (int w = 0; w < 16; ++w) s += scpart[w][tid];
        scores[(size_t)b * T + t0 + tid] = s;
    }
}

__global__ __launch_bounds__(256) void softmax_kernel(const float* __restrict__ sc,
                                                      float* __restrict__ out) {
    int b = blockIdx.x;
    int tid = threadIdx.x;
    int wave = tid >> 6, lane = tid & 63;
    const float* row = sc + (size_t)b * T;
    float vals[8];
    float m = -1e30f;
#pragma unroll
    for (int i = 0; i < 8; ++i) { vals[i] = row[tid + 256 * i]; m = fmaxf(m, vals[i]); }
#pragma unroll
    for (int s = 1; s < 64; s <<= 1) m = fmaxf(m, __shfl_xor(m, s));
    __shared__ float red[4];
    __shared__ float red2[4];
    if (lane == 0) red[wave] = m;
    __syncthreads();
    m = fmaxf(fmaxf(red[0], red[1]), fmaxf(red[2], red[3]));
    float sum = 0.f;
#pragma unroll
    for (int i = 0; i < 8; ++i) { vals[i] = expf(vals[i] - m); sum += vals[i]; }
#pragma unroll
    for (int s = 1; s < 64; s <<= 1) sum += __shfl_xor(sum, s);
    if (lane == 0) red2[wave] = sum;
    __syncthreads();
    sum = red2[0] + red2[1] + red2[2] + red2[3];
    float inv = 1.0f / sum;
#pragma unroll
    for (int i = 0; i < 8; ++i) out[(size_t)b * T + tid + 256 * i] = vals[i] * inv;
}

extern "C" void kernel_launch(void* const* d_in, const int* in_sizes, int n_in,
                              void* d_out, int out_size, void* d_ws, size_t ws_size,
                              hipStream_t stream) {
    (void)in_sizes; (void)n_in; (void)out_size; (void)ws_size;
    const float* hidden = (const float*)d_in[0];   // [1,B,H]
    const float* enc    = (const float*)d_in[1];   // [B,T,H]
    const float* W      = (const float*)d_in[2];   // [H,2H]
    const float* bias   = (const float*)d_in[3];   // [H]
    const float* v      = (const float*)d_in[4];   // [H]
    float* out = (float*)d_out;                    // [B,1,T]

    unsigned short* Wp = (unsigned short*)d_ws;                               // 2 MB
    float* hp = (float*)((char*)d_ws + 2 * 1024 * 1024);                      // 128 KB
    float* sc = (float*)((char*)d_ws + 2 * 1024 * 1024 + 128 * 1024);         // 256 KB

    prep_w_kernel<<<dim3(512), dim3(256), 0, stream>>>(W, Wp);
    prep_hp_kernel<<<dim3(16, B), dim3(256), 0, stream>>>(hidden, W, bias, hp);
    energy_kernel<<<dim3(T / BM, B), dim3(1024), 0, stream>>>(enc, hp, v, Wp, sc);
    softmax_kernel<<<dim3(B), dim3(256), 0, stream>>>(sc, out);
}

// Round 15
// 267.277 us; speedup vs baseline: 1.1481x; 1.1481x over previous
//
#include <hip/hip_runtime.h>
#include <hip/hip_bf16.h>

#define H 1024
#define T 2048
#define B 32
#define BM 128        // rows per block
#define BN 512        // cols per block
#define NCOLT 2       // col tiles (1024/BN)
#define BK 32         // k per LDS chunk
#define NCH 32        // H / BK

typedef __attribute__((ext_vector_type(8))) __bf16 bf16x8;
typedef __attribute__((ext_vector_type(16))) float f32x16;
typedef __attribute__((ext_vector_type(4))) unsigned short u16x4;
typedef __attribute__((ext_vector_type(8))) unsigned short u16x8;

__device__ __forceinline__ unsigned short f2bf(float f) {
    unsigned int x = __float_as_uint(f);
    x += 0x7fffu + ((x >> 16) & 1u);
    return (unsigned short)(x >> 16);
}

__device__ __forceinline__ float fast_tanh(float x) {
    float t = __expf(2.0f * x);
    return 1.0f - 2.0f * __builtin_amdgcn_rcpf(t + 1.0f);
}

// async global->LDS, 16B per lane; LDS dest is wave-uniform base + lane*16 (HW rule)
__device__ __forceinline__ void gload16(const void* g, void* l) {
    __builtin_amdgcn_global_load_lds((const __attribute__((address_space(1))) void*)g,
                                     (__attribute__((address_space(3))) void*)l, 16, 0, 0);
}

// Pack W2 = W[:, H:2H] into bf16, layout Wp[kg][n][8] (kg = k>>3), 16B per (kg,n)
__global__ __launch_bounds__(256) void prep_w_kernel(const float* __restrict__ W,
                                                     unsigned short* __restrict__ Wp) {
    int gid = blockIdx.x * 256 + threadIdx.x;   // 131072 total
    int n = gid & (H - 1);
    int kg = gid >> 10;                          // 0..127
    const float* srcp = W + (size_t)n * (2 * H) + H + kg * 8;
    float4 f0 = *(const float4*)(srcp);
    float4 f1 = *(const float4*)(srcp + 4);
    u16x8 o;
    o[0] = f2bf(f0.x); o[1] = f2bf(f0.y); o[2] = f2bf(f0.z); o[3] = f2bf(f0.w);
    o[4] = f2bf(f1.x); o[5] = f2bf(f1.y); o[6] = f2bf(f1.z); o[7] = f2bf(f1.w);
    *(u16x8*)(Wp + (size_t)gid * 8) = o;
}

// hp[b][h] = sum_d hidden[b][d]*W[h][d] + bias[h], k-split x4 + shuffle reduce
__global__ __launch_bounds__(256) void prep_hp_kernel(const float* __restrict__ hidden,
                                                      const float* __restrict__ W,
                                                      const float* __restrict__ bias,
                                                      float* __restrict__ hp) {
    int b = blockIdx.y;
    int t = threadIdx.x;
    int h = blockIdx.x * 64 + (t >> 2);
    int kq = t & 3;
    const float* hid = hidden + (size_t)b * H + kq * 256;
    const float* wr = W + (size_t)h * (2 * H) + kq * 256;
    float acc = 0.f;
#pragma unroll 4
    for (int d = 0; d < 256; d += 4) {
        float4 wv = *(const float4*)(wr + d);
        float4 hv = *(const float4*)(hid + d);
        acc += wv.x * hv.x + wv.y * hv.y + wv.z * hv.z + wv.w * hv.w;
    }
    acc += __shfl_xor(acc, 1);
    acc += __shfl_xor(acc, 2);
    if (kq == 0) hp[(size_t)b * H + h] = acc + bias[h];
}

#define MFMA32(A, Bv, C) __builtin_amdgcn_mfma_f32_32x32x16_bf16(A, Bv, C, 0, 0, 0)

// Block = (128-row t-tile, 512-col tile, b); 1024 thr = 16 waves as 2(row-half) x
// 8(col-group); wave = 64 rows x 64 cols, acc = 4 x f32x16 = 64 AGPR.
// B: bf16 Wp staged via global_load_lds (width 16) into LDS [kslot 0..3][col 0..511]
//    (linear dest, contiguous src) -- no VGPR/VALU on the B path at all.
// A: enc fp32 reg-staged -> bf16 LDS, pages ks 0..3, addr = ks*2048 + ((row^(2ks))<<4).
// Both next-iter loads issue at iter top (full-iter latency cover), one
// __syncthreads per iter. colt = fastest grid dim so col-twins share enc via L2/L3.
__global__ __launch_bounds__(1024, 4) void energy_kernel(const float* __restrict__ enc,
                                                         const float* __restrict__ hp,
                                                         const float* __restrict__ vvec,
                                                         const unsigned short* __restrict__ Wp,
                                                         float* __restrict__ sc_part) {
    __shared__ __align__(16) unsigned short Abuf[2][BM * BK];        // 2 x 8 KB
    __shared__ __align__(16) unsigned short Bbuf[2][4 * BN * 8];     // 2 x 32 KB
    __shared__ float scpart[16][64];                                 // 4 KB

    const int tid = threadIdx.x;
    const int colt = blockIdx.x;
    const int t0 = blockIdx.y * BM;
    const int b = blockIdx.z;
    const int c0 = colt * BN;
    const int wave = tid >> 6;
    const int lane = tid & 63;
    const int l31 = lane & 31;
    const int hi = lane >> 5;
    const int wr = wave >> 3;      // row half 0..1
    const int wc = wave & 7;       // col group 0..7

    // ---- A staging map: thread -> (row = tid>>3, kquad = tid&7), 16B fp32 -> 8B bf16
    const int st_row = tid >> 3;
    const int st_q = tid & 7;
    const int st_ks = st_q >> 1, st_half = st_q & 1;
    const float* st_src = enc + ((size_t)b * T + t0 + st_row) * H + st_q * 4;
    char* Ab0 = (char*)&Abuf[0][0];
    const int st_off = st_ks * 2048 + ((st_row ^ (st_ks << 1)) << 4) + st_half * 8;

    // ---- B staging map: 2 gload_lds per wave per iter; call i = wave*2+c -> (s=i>>3, ch=i&7)
    char* Bb0 = (char*)&Bbuf[0][0];
    const int i0 = wave * 2;
    const int boff0 = (i0 >> 3) * 8192 + (i0 & 7) * 1024;
    const int boff1 = ((i0 + 1) >> 3) * 8192 + ((i0 + 1) & 7) * 1024;
    const unsigned short* bsrc0 = Wp + (size_t)(i0 >> 3) * (H * 8) +
                                  (size_t)(c0 + (i0 & 7) * 64 + lane) * 8;
    const unsigned short* bsrc1 = Wp + (size_t)((i0 + 1) >> 3) * (H * 8) +
                                  (size_t)(c0 + ((i0 + 1) & 7) * 64 + lane) * 8;

    f32x16 acc00, acc01, acc10, acc11;
#pragma unroll
    for (int i = 0; i < 16; ++i) { acc00[i] = 0.f; acc01[i] = 0.f; acc10[i] = 0.f; acc11[i] = 0.f; }

    const int r0 = wr * 64 + l31;
    const int r1 = wr * 64 + 32 + l31;

    // ---- prologue: stage A[0] (reg path) + B[0] (gload_lds) ----
    {
        float4 f = *(const float4*)(st_src);
        u16x4 o;
        o[0] = f2bf(f.x); o[1] = f2bf(f.y); o[2] = f2bf(f.z); o[3] = f2bf(f.w);
        *(u16x4*)(Ab0 + st_off) = o;
    }
    gload16(bsrc0, Bb0 + boff0);
    gload16(bsrc1, Bb0 + boff1);
    __syncthreads();

    for (int j = 0; j < NCH; ++j) {
        const char* Ab = Ab0 + (j & 1) * 8192;
        const char* Bb = Bb0 + (j & 1) * 32768;
        float4 f;
        const bool pf = (j < NCH - 1);
        if (pf) {
            const size_t kgadv = (size_t)(j + 1) * 4 * (H * 8);
            char* Bbw = Bb0 + ((j + 1) & 1) * 32768;
            gload16(bsrc0 + kgadv, Bbw + boff0);
            gload16(bsrc1 + kgadv, Bbw + boff1);
            f = *(const float4*)(st_src + (size_t)(j + 1) * BK);
        }
#pragma unroll
        for (int t = 0; t < 2; ++t) {
            const int ks = t * 2 + hi;
            const char* ap = Ab + ks * 2048;
            bf16x8 a0 = *(const bf16x8*)(ap + ((r0 ^ (ks << 1)) << 4));
            bf16x8 a1 = *(const bf16x8*)(ap + ((r1 ^ (ks << 1)) << 4));
            const char* bp = Bb + ks * 8192 + (wc * 64 + l31) * 16;
            bf16x8 b0 = *(const bf16x8*)(bp);
            bf16x8 b1 = *(const bf16x8*)(bp + 512);
            __builtin_amdgcn_s_setprio(1);
            acc00 = MFMA32(a0, b0, acc00);
            acc01 = MFMA32(a0, b1, acc01);
            acc10 = MFMA32(a1, b0, acc10);
            acc11 = MFMA32(a1, b1, acc11);
            __builtin_amdgcn_s_setprio(0);
        }
        if (pf) {
            u16x4 o;
            o[0] = f2bf(f.x); o[1] = f2bf(f.y); o[2] = f2bf(f.z); o[3] = f2bf(f.w);
            *(u16x4*)(Ab0 + ((j + 1) & 1) * 8192 + st_off) = o;
        }
        __syncthreads();
    }

    // ---- fused epilogue: tanh + v-dot over this wave's 64 cols ----
    const size_t bH = (size_t)b * H;
    const int col0 = c0 + wc * 64 + l31;
    const int col1 = col0 + 32;
    const float hp0 = hp[bH + col0], hp1 = hp[bH + col1];
    const float v0 = vvec[col0], v1 = vvec[col1];
    float psc[2][16];
#pragma unroll
    for (int r = 0; r < 16; ++r) {
        psc[0][r] = v0 * fast_tanh(acc00[r] + hp0) + v1 * fast_tanh(acc01[r] + hp1);
        psc[1][r] = v0 * fast_tanh(acc10[r] + hp0) + v1 * fast_tanh(acc11[r] + hp1);
    }

#pragma unroll
    for (int rg = 0; rg < 2; ++rg)
#pragma unroll
        for (int r = 0; r < 16; ++r) {
            float s = psc[rg][r];
            s += __shfl_xor(s, 1);
            s += __shfl_xor(s, 2);
            s += __shfl_xor(s, 4);
            s += __shfl_xor(s, 8);
            s += __shfl_xor(s, 16);
            psc[rg][r] = s;
        }
    if (l31 == 0) {
#pragma unroll
        for (int rg = 0; rg < 2; ++rg)
#pragma unroll
            for (int r = 0; r < 16; ++r) {
                int m = rg * 32 + (r & 3) + 8 * (r >> 2) + 4 * hi;   // 0..63 in wave rows
                scpart[wave][m] = psc[rg][r];
            }
    }
    __syncthreads();
    if (tid < BM) {
        const int wrr = tid >> 6;          // row half of this output row
        const int loc = tid & 63;
        float s = 0.f;
#pragma unroll
        for (int c = 0; c < 8; ++c) s += scpart[wrr * 8 + c][loc];
        sc_part[((size_t)colt * B + b) * T + t0 + tid] = s;
    }
}

__global__ __launch_bounds__(256) void softmax_kernel(const float* __restrict__ sc,
                                                      float* __restrict__ out) {
    int b = blockIdx.x;
    int tid = threadIdx.x;
    int wave = tid >> 6, lane = tid & 63;
    const float* r0 = sc + (size_t)b * T;
    const float* r1 = sc + ((size_t)B + b) * T;
    float vals[8];
    float m = -1e30f;
#pragma unroll
    for (int i = 0; i < 8; ++i) {
        int idx = tid + 256 * i;
        vals[i] = r0[idx] + r1[idx];
        m = fmaxf(m, vals[i]);
    }
#pragma unroll
    for (int s = 1; s < 64; s <<= 1) m = fmaxf(m, __shfl_xor(m, s));
    __shared__ float red[4];
    __shared__ float red2[4];
    if (lane == 0) red[wave] = m;
    __syncthreads();
    m = fmaxf(fmaxf(red[0], red[1]), fmaxf(red[2], red[3]));
    float sum = 0.f;
#pragma unroll
    for (int i = 0; i < 8; ++i) { vals[i] = expf(vals[i] - m); sum += vals[i]; }
#pragma unroll
    for (int s = 1; s < 64; s <<= 1) sum += __shfl_xor(sum, s);
    if (lane == 0) red2[wave] = sum;
    __syncthreads();
    sum = red2[0] + red2[1] + red2[2] + red2[3];
    float inv = 1.0f / sum;
#pragma unroll
    for (int i = 0; i < 8; ++i) out[(size_t)b * T + tid + 256 * i] = vals[i] * inv;
}

extern "C" void kernel_launch(void* const* d_in, const int* in_sizes, int n_in,
                              void* d_out, int out_size, void* d_ws, size_t ws_size,
                              hipStream_t stream) {
    (void)in_sizes; (void)n_in; (void)out_size; (void)ws_size;
    const float* hidden = (const float*)d_in[0];   // [1,B,H]
    const float* enc    = (const float*)d_in[1];   // [B,T,H]
    const float* W      = (const float*)d_in[2];   // [H,2H]
    const float* bias   = (const float*)d_in[3];   // [H]
    const float* v      = (const float*)d_in[4];   // [H]
    float* out = (float*)d_out;                    // [B,1,T]

    unsigned short* Wp = (unsigned short*)d_ws;                               // 2 MB
    float* hp = (float*)((char*)d_ws + 2 * 1024 * 1024);                      // 128 KB
    float* sc = (float*)((char*)d_ws + 2 * 1024 * 1024 + 128 * 1024);         // 512 KB (2 partials)

    prep_w_kernel<<<dim3(512), dim3(256), 0, stream>>>(W, Wp);
    prep_hp_kernel<<<dim3(16, B), dim3(256), 0, stream>>>(hidden, W, bias, hp);
    energy_kernel<<<dim3(NCOLT, T / BM, B), dim3(1024), 0, stream>>>(enc, hp, v, Wp, sc);
    softmax_kernel<<<dim3(B), dim3(256), 0, stream>>>(sc, out);
}